// Round 12
// baseline (87.649 us; speedup 1.0000x reference)
//
#include <hip/hip_runtime.h>
#include <math.h>

#define BB 16
#define HH 256
#define WW 256
#define NN (BB*HH*WW)
#define SCAN_INIT 300
#define BIGR 100000
#define NBLK 1024          // fused_row_k grid
#define FWS 17             // fwd_s padded stride (bank-conflict fix)

static __device__ constexpr float INF_EDT = 131072.0f; // H*H + W*W, exact in fp32

__device__ __forceinline__ float sigmoidf(float v){ return 1.0f/(1.0f+expf(-v)); }
// stable log_sigmoid(v) = min(v,0) - log1p(exp(-|v|))
__device__ __forceinline__ float logsigf(float v){
  return fminf(v, 0.0f) - log1pf(expf(-fabsf(v)));
}
__device__ __forceinline__ float min3f(float a, float b, float c){
  return fminf(fminf(a, b), c);   // clang fuses to v_min3_f32
}

// -------------------------------------------------------------------------
// Column EDT, segmented scan (exact for binary seeds).
// g(x,j) = Dcol(x,j)^2, Dcol = dist to nearest seed in column j, or 131072
// exactly if the column has none (brute force: INF + 0 at i=x).
// 256 blocks x 256 thr: block = (image b, 16-column group); thread =
// (col = t&15, seg = t>>4), seg scans rows [16*seg, 16*seg+16).
// Cross-segment: nearest seed above = max(last[s<seg]), below = min(first[s>seg]).
// Block 0 also zeroes the last-block-done counters for fused_row_k
// (stream-ordered before use; re-zeroed every launch).
// Integer-valued fp32 -> bit-identical to the reference brute force.
// -------------------------------------------------------------------------
__global__ __launch_bounds__(256) void edt_cols_scan(const float* __restrict__ tgt,
                                                     float* __restrict__ gA,
                                                     float* __restrict__ gB,
                                                     int* __restrict__ hp_blk,
                                                     int* __restrict__ cnt){
  __shared__ unsigned int fwd_s[HH*FWS];    // [row][col] stride-17: 2-way banks
  __shared__ int lastp_s[16*16], firstp_s[16*16];
  __shared__ int lastn_s[16*16], firstn_s[16*16];
  const int b   = blockIdx.x >> 4;
  const int j0  = (blockIdx.x & 15) << 4;
  const int t   = threadIdx.x;
  const int col = t & 15, seg = t >> 4;
  const int j = j0 + col, r0 = seg << 4;

  if (blockIdx.x == 0 && t < 65) cnt[t] = 0;   // 64 group counters + 1 final

  int dp = SCAN_INIT, dn = SCAN_INIT;
  int firstp = BIGR, lastp = -BIGR, firstn = BIGR, lastn = -BIGR;
  #pragma unroll 4
  for (int i = 0; i < 16; ++i){
    const int gi = r0 + i;
    const float tv = tgt[(b*HH + gi)*WW + j];
    const bool s = tv > 0.5f;
    dp = s ? 0 : dp + 1;
    dn = s ? dn + 1 : 0;
    if (s){ lastp = gi; if (firstp == BIGR) firstp = gi; }
    else  { lastn = gi; if (firstn == BIGR) firstn = gi; }
    fwd_s[gi*FWS + col] = ((unsigned)dp << 16) | (unsigned)dn;
  }
  lastp_s[seg*16+col] = lastp; firstp_s[seg*16+col] = firstp;
  lastn_s[seg*16+col] = lastn; firstn_s[seg*16+col] = firstn;
  __syncthreads();

  // cross-segment nearest-seed rows for this thread's segment
  int upP=-BIGR, dnP=BIGR, upN=-BIGR, dnN=BIGR, allP=-BIGR, allN=-BIGR;
  #pragma unroll
  for (int s2 = 0; s2 < 16; ++s2){
    const int lp = lastp_s[s2*16+col], fp = firstp_s[s2*16+col];
    const int ln = lastn_s[s2*16+col], fn = firstn_s[s2*16+col];
    allP = max(allP, lp); allN = max(allN, ln);
    if (s2 < seg){ upP = max(upP, lp); upN = max(upN, ln); }
    if (s2 > seg){ dnP = min(dnP, fp); dnN = min(dnN, fn); }
  }
  const bool colp = allP >= 0;
  const bool coln = allN >= 0;
  if (t < 64){                     // wave 0 spans all 16 columns (x4 segs)
    unsigned long long bal = __ballot(colp);
    if (t == 0) hp_blk[blockIdx.x] = bal ? 1 : 0;
  }

  int bp = SCAN_INIT, bn = SCAN_INIT;
  #pragma unroll 4
  for (int i = 15; i >= 0; --i){
    const int gi = r0 + i;
    const unsigned f = fwd_s[gi*FWS + col];
    const int fp = (int)(f >> 16), fn = (int)(f & 0xffffu);
    bp = (fp == 0) ? 0 : bp + 1;
    bn = (fn == 0) ? 0 : bn + 1;
    int Dp = min(min(fp, bp), min(gi - upP, dnP - gi));
    int Dn = min(min(fn, bn), min(gi - upN, dnN - gi));
    Dp = min(Dp, 512); Dn = min(Dn, 512);  // never binds when col has a seed
    const int o = (b*HH + gi)*WW + j;
    gA[o] = colp ? (float)(Dp*Dp) : INF_EDT;
    gB[o] = coln ? (float)(Dn*Dn) : INF_EDT;
  }
}

// -------------------------------------------------------------------------
// Fused row pass + last-block final reduce.
// Per 4-row strip: windowed min-plus EDT pass 2 (only |y-j| <= sqrt(g(x,y))
// can improve; clamp-overrun candidates never undercut the exact min),
// sobel on sigmoid(x) and t (replicate pad, 6-row staged halo), and the
// focal+CE+boundary epilogue -> one scalar partial per block.
// Completion tracking: 64 group counters (16 blocks each) -> 1 final counter;
// the last block overall reduces the 1024 partials (same order as the old
// finalize_k -> bit-identical) and writes out[0]. Agent-scope release/acquire
// on partials for cross-XCD visibility.
// -------------------------------------------------------------------------
__global__ __launch_bounds__(256) void fused_row_k(const float* __restrict__ inp,
    const float* __restrict__ tgt, const float* __restrict__ gA, const float* __restrict__ gB,
    const int* __restrict__ hp_blk, float* __restrict__ part, int* __restrict__ cnt,
    float* __restrict__ out){
  __shared__ __align__(16) float ga_s[4][WW];
  __shared__ __align__(16) float gb_s[4][WW];
  __shared__ __align__(16) float ss[6][WW];   // sigmoid(x), rows x0-1..x0+4 clamped
  __shared__ __align__(16) float tt[6][WW];   // t, same rows
  __shared__ float red[4];
  __shared__ int winner_s;
  const int b  = blockIdx.x >> 6;
  const int x0 = (blockIdx.x & 63) << 2;
  const int t  = threadIdx.x;
  const int g = t >> 6, l = t & 63;

  {
    const int l4 = l << 2;
    const int base = (b*HH + x0 + g)*WW + l4;
    *(float4*)&ga_s[g][l4] = *(const float4*)&gA[base];
    *(float4*)&gb_s[g][l4] = *(const float4*)&gB[base];
    for (int k = g; k < 6; k += 4){
      int gr = x0 - 1 + k; gr = gr < 0 ? 0 : (gr > HH-1 ? HH-1 : gr);
      const float4 xv = *(const float4*)&inp[(b*HH + gr)*WW + l4];
      const float4 tv = *(const float4*)&tgt[(b*HH + gr)*WW + l4];
      float4 sv; sv.x = sigmoidf(xv.x); sv.y = sigmoidf(xv.y);
      sv.z = sigmoidf(xv.z); sv.w = sigmoidf(xv.w);
      *(float4*)&ss[k][l4] = sv;
      *(float4*)&tt[k][l4] = tv;
    }
  }
  __syncthreads();

  int hp_ = 0;
  #pragma unroll
  for (int i = 0; i < 16; ++i) hp_ |= hp_blk[b*16 + i];

  const int y = t;
  const int cm = y ? y-1 : 0, cp = y < WW-1 ? y+1 : WW-1;

  // sliding 3x3 register window for sobel
  float a0m = ss[0][cm], a0c = ss[0][y], a0p = ss[0][cp];
  float a1m = ss[1][cm], a1c = ss[1][y], a1p = ss[1][cp];
  float b0m = tt[0][cm], b0c = tt[0][y], b0p = tt[0][cp];
  float b1m = tt[1][cm], b1c = tt[1][y], b1p = tt[1][cp];

  float acc = 0.0f;
  #pragma unroll
  for (int r = 0; r < 4; ++r){
    // ---- EDT pass 2, windowed ----
    float dpv = ga_s[r][y];
    float dnv = gb_s[r][y];
    int wm = (int)sqrtf(fmaxf(dpv, dnv)) + 1; if (wm > 255) wm = 255;
    for (int dj = 1; dj <= wm; dj += 4){
      #pragma unroll
      for (int u = 0; u < 4; ++u){
        const int d = dj + u;
        const float d2 = (float)(d*d);
        const int jl = (y - d) < 0   ? 0   : y - d;
        const int jr = (y + d) > 255 ? 255 : y + d;
        dpv = min3f(dpv, ga_s[r][jl] + d2, ga_s[r][jr] + d2);
        dnv = min3f(dnv, gb_s[r][jl] + d2, gb_s[r][jr] + d2);
      }
    }
    // ---- sobel (rows r..r+2 of staged halo) ----
    const float a2m = ss[r+2][cm], a2c = ss[r+2][y], a2p = ss[r+2][cp];
    const float b2m = tt[r+2][cm], b2c = tt[r+2][y], b2p = tt[r+2][cp];
    const float gxs = ((a0p-a0m) + 2.0f*(a1p-a1m) + (a2p-a2m)) * 0.125f;
    const float gys = ((a2m-a0m) + 2.0f*(a2c-a0c) + (a2p-a0p)) * 0.125f;
    const float mags = sqrtf(gxs*gxs + gys*gys + 1e-6f);
    const float gxt = ((b0p-b0m) + 2.0f*(b1p-b1m) + (b2p-b2m)) * 0.125f;
    const float gyt = ((b2m-b0m) + 2.0f*(b2c-b0c) + (b2p-b0p)) * 0.125f;
    const float magt = sqrtf(gxt*gxt + gyt*gyt + 1e-6f);
    acc += fabsf(mags - magt);
    a0m=a1m; a0c=a1c; a0p=a1p; a1m=a2m; a1c=a2c; a1p=a2p;
    b0m=b1m; b0c=b1c; b0p=b1p; b1m=b2m; b1c=b2c; b1p=b2p;

    // ---- focal / ce / boundary ----
    const float xv = inp[(b*HH + x0 + r)*WW + y];   // L1/L2-hot reload
    const float tv = tt[r+1][y];
    const float sg = ss[r+1][y];
    float sdf = sqrtf(dnv) - sqrtf(dpv);            // d_out - d_in
    sdf = hp_ ? sdf : 0.0f;
    acc += (sg - tv) * sdf;
    const float lp = logsigf(xv);
    const float ln = logsigf(-xv);
    const float bce = -(tv*lp + (1.0f - tv)*ln);
    const float pt = expf(-bce);
    const float om = 1.0f - pt;
    acc += 0.8f * om * om * bce;                    // focal (ALPHA=0.8, GAMMA=2)
    acc += bce;                                     // ce with POS_W=1 == bce
  }

  #pragma unroll
  for (int o = 32; o > 0; o >>= 1) acc += __shfl_down(acc, o);
  if (l == 0) red[g] = acc;
  __syncthreads();

  // publish partial + two-level last-block-done
  if (t == 0){
    const float p = red[0]+red[1]+red[2]+red[3];
    __hip_atomic_store(&part[blockIdx.x], p, __ATOMIC_RELEASE, __HIP_MEMORY_SCOPE_AGENT);
    int win = 0;
    const int grp = blockIdx.x >> 4;            // 64 groups of 16 blocks
    if (atomicAdd(&cnt[grp], 1) == 15){         // last in group
      if (atomicAdd(&cnt[64], 1) == 63) win = 1; // last overall
    }
    winner_s = win;
  }
  __syncthreads();

  if (winner_s){
    float s = 0.0f;
    #pragma unroll
    for (int i = t; i < NBLK; i += 256)
      s += __hip_atomic_load(&part[i], __ATOMIC_ACQUIRE, __HIP_MEMORY_SCOPE_AGENT);
    #pragma unroll
    for (int o = 32; o > 0; o >>= 1) s += __shfl_down(s, o);
    if (l == 0) red[g] = s;
    __syncthreads();
    if (t == 0) out[0] = (red[0]+red[1]+red[2]+red[3]) * (1.0f/(float)NN);
  }
}

extern "C" void kernel_launch(void* const* d_in, const int* in_sizes, int n_in,
                              void* d_out, int out_size, void* d_ws, size_t ws_size,
                              hipStream_t stream){
  const float* inp = (const float*)d_in[0];
  const float* tgt = (const float*)d_in[1];
  float* out = (float*)d_out;
  float* gA   = (float*)d_ws;         // B*H*W fp32, seeds = pos
  float* gB   = gA + NN;              // B*H*W fp32, seeds = ~pos
  float* part = gB + NN;              // 1024 block partials
  int* hp_blk = (int*)(part + NBLK);  // 256 per-scan-block pos flags
  int* cnt    = hp_blk + 256;         // 64 group counters + 1 final

  edt_cols_scan<<<BB*16, 256, 0, stream>>>(tgt, gA, gB, hp_blk, cnt);
  fused_row_k<<<NBLK, 256, 0, stream>>>(inp, tgt, gA, gB, hp_blk, part, cnt, out);
}